// Round 12
// baseline (253.459 us; speedup 1.0000x reference)
//
#include <hip/hip_runtime.h>
#include <hip/hip_bf16.h>

#define EPS 1e-5f

typedef __bf16 bf16x8 __attribute__((ext_vector_type(8)));
typedef __bf16 bf16x4 __attribute__((ext_vector_type(4)));
typedef float f32x4 __attribute__((ext_vector_type(4)));

__device__ __forceinline__ float hsw(float x){
    float t = fminf(fmaxf(x + 3.f, 0.f), 6.f);
    return x * t * (1.f/6.f);
}
__device__ __forceinline__ float sigm(float x){ return 1.f/(1.f + expf(-x)); }

// shift_in analytically: s = 64*((v+c)%25)+c -> x[n,c,t,v] = x0[n,c,t,(v+c)%25].
// K1: TCH=6, 8 blocks/CU, coalesced t0_part stores ([u*64+c] layout).
__global__ __launch_bounds__(256, 8) void k1_viewtime(
    const float* __restrict__ x0, const float* __restrict__ Wv,
    const float* __restrict__ Wt, float* __restrict__ view_pre,
    float* __restrict__ t0_part, float* __restrict__ view_part)
{
    const int tc = blockIdx.x, n = blockIdx.y, t0 = tc*6;
    const int tid = threadIdx.x;
    __shared__ alignas(16) unsigned char smem[64*154*2];   // 19712 B
    __shared__ float rs[8];
    __shared__ float WvL[32];
    __hip_bfloat16* lx = (__hip_bfloat16*)smem;   // [c][tt*25+u], stride 154 (77 dw, odd)
    float* red = (float*)smem;                    // [ug*64+c][7] after lx dead
    if (tid < 25) WvL[tid] = Wv[tid];
    const float* xb = x0 + n*480000 + t0*25;
    for (int i = tid; i < 4800; i += 256){
        int row = i/75, c2 = i - row*75;
        float2 f = *reinterpret_cast<const float2*>(xb + row*7500 + c2*2);
        union { unsigned u; __hip_bfloat16 h[2]; } pk;
        pk.h[0]=__float2bfloat16(f.x); pk.h[1]=__float2bfloat16(f.y);
        *reinterpret_cast<unsigned*>(&lx[row*154 + c2*2]) = pk.u;
    }
    float wt[6];
    #pragma unroll
    for (int tt=0;tt<6;tt++) wt[tt] = Wt[t0+tt];
    __syncthreads();
    const int c = tid & 63, ug = tid >> 6;
    const int cm = c - ((c>=50)?50:((c>=25)?25:0));
    float vacc[6] = {0.f,0.f,0.f,0.f,0.f,0.f};
    for (int k=0;k<7;k++){
        int u = ug + 4*k;
        if (u < 25){
            int mm = u - cm; if (mm < 0) mm += 25;
            float wv = WvL[mm];
            int base = c*154 + u;
            float tacc = 0.f;
            #pragma unroll
            for (int tt=0;tt<6;tt++){
                float val = __bfloat162float(lx[base + tt*25]);
                tacc += wt[tt]*val;
                vacc[tt] += wv*val;
            }
            t0_part[(n*50+tc)*1600 + u*64 + c] = tacc;
        }
    }
    __syncthreads();
    #pragma unroll
    for (int tt=0;tt<6;tt++) red[(ug*64+c)*7 + tt] = vacc[tt];
    __syncthreads();
    float vs=0.f, vq=0.f;
    for (int i = tid; i < 384; i += 256){
        int tt = i>>6, c2 = i&63;
        float tot = red[(0*64+c2)*7+tt]+red[(1*64+c2)*7+tt]
                  + red[(2*64+c2)*7+tt]+red[(3*64+c2)*7+tt];
        view_pre[n*19200 + c2*300 + t0+tt] = tot;
        vs += tot; vq += tot*tot;
    }
    #pragma unroll
    for (int o=32;o>0;o>>=1){ vs += __shfl_down(vs,o); vq += __shfl_down(vq,o); }
    if ((tid&63)==0){ rs[(tid>>6)*2]=vs; rs[(tid>>6)*2+1]=vq; }
    __syncthreads();
    if (tid==0){
        view_part[(n*50+tc)*2]   = rs[0]+rs[2]+rs[4]+rs[6];
        view_part[(n*50+tc)*2+1] = rs[1]+rs[3]+rs[5]+rs[7];
    }
}

// K2a: reduce T0 partials over 50 chunks -> time_pre [n][u*64+c]; stat partials.
__global__ __launch_bounds__(256) void k2a_timereduce(
    const float* __restrict__ t0_part, float* __restrict__ time_pre,
    float* __restrict__ tstat_part)
{
    int g = blockIdx.x*256 + threadIdx.x;   // [0, 102400)
    int n = g / 1600, r = g % 1600;
    float s = 0.f;
    for (int tc=0; tc<50; tc++) s += t0_part[(n*50+tc)*1600 + r];
    time_pre[g] = s;
    float a = s, b = s*s;
    __shared__ float ls[8];
    #pragma unroll
    for (int o=32;o>0;o>>=1){ a += __shfl_down(a,o); b += __shfl_down(b,o); }
    int wid = threadIdx.x >> 6;
    if ((threadIdx.x & 63) == 0){ ls[wid*2] = a; ls[wid*2+1] = b; }
    __syncthreads();
    if (threadIdx.x == 0){
        tstat_part[blockIdx.x*2]   = ls[0]+ls[2]+ls[4]+ls[6];
        tstat_part[blockIdx.x*2+1] = ls[1]+ls[3]+ls[5]+ls[7];
    }
}

// K2b: final scalar BN stats for view/time branches.
__global__ __launch_bounds__(256) void k2b_finstats(
    const float* __restrict__ view_part, const float* __restrict__ tstat_part,
    float* __restrict__ fin)
{
    float acc[4] = {0.f,0.f,0.f,0.f};
    for (int i=threadIdx.x; i<3200; i+=256){ acc[0] += view_part[2*i]; acc[1] += view_part[2*i+1]; }
    for (int i=threadIdx.x; i<400;  i+=256){ acc[2] += tstat_part[2*i]; acc[3] += tstat_part[2*i+1]; }
    __shared__ float ls[4][4];
    int wid = threadIdx.x>>6, lane = threadIdx.x&63;
    #pragma unroll
    for (int j=0;j<4;j++){
        float a = acc[j];
        #pragma unroll
        for (int o=32;o>0;o>>=1) a += __shfl_down(a,o);
        if (lane==0) ls[j][wid] = a;
    }
    __syncthreads();
    if (threadIdx.x==0){
        float VS=ls[0][0]+ls[0][1]+ls[0][2]+ls[0][3];
        float VQ=ls[1][0]+ls[1][1]+ls[1][2]+ls[1][3];
        float TS=ls[2][0]+ls[2][1]+ls[2][2]+ls[2][3];
        float TQ=ls[3][0]+ls[3][1]+ls[3][2]+ls[3][3];
        float vm = VS / 1228800.f;
        float vvar = fmaxf(VQ/1228800.f - vm*vm, 0.f);
        float tm = TS / 102400.f;
        float tvar = fmaxf(TQ/102400.f - tm*tm, 0.f);
        fin[0] = vm; fin[1] = rsqrtf(vvar + EPS);
        fin[2] = tm; fin[3] = rsqrtf(tvar + EPS);
    }
}

// K3: sum2_raw[n,d,l] = sum_ch Ws[d,ch]*F(n, ch*325+l); per-d stat partials.
__global__ __launch_bounds__(256) void k3_conv(
    const float* __restrict__ time_pre, const float* __restrict__ view_pre,
    const float* __restrict__ fin, const float* __restrict__ Ws,
    const float* __restrict__ g_t, const float* __restrict__ be_t,
    const float* __restrict__ g_v, const float* __restrict__ be_v,
    float* __restrict__ sum2_raw, float* __restrict__ chan_part)
{
    const int n = blockIdx.y, lc = blockIdx.x;
    const int tid = threadIdx.x, lane = tid & 63, w = tid >> 6;
    const int l = lc*64 + lane;
    __shared__ float Ft[64][64];    // [ch][l-lane]
    __shared__ float Wst[64][64];   // [ch][d]
    for (int i = tid; i < 4096; i += 256){
        int d = i>>6, ch = i&63;
        Wst[ch][d] = Ws[i];
    }
    const float vm = fin[0], vi = fin[1], tm = fin[2], ti = fin[3];
    const float gt = g_t[0]*ti, bt = be_t[0] - tm*g_t[0]*ti;
    const float gv = g_v[0]*vi, bv = be_v[0] - vm*g_v[0]*vi;
    const bool lval = (l < 325);
    for (int k=0;k<16;k++){
        int ch = w + 4*k;
        float val = 0.f;
        if (lval){
            int idx = ch*325 + l;
            if (idx < 1600){
                int cc = idx/25, vv = idx - cc*25;
                int cmm = cc - ((cc>=50)?50:((cc>=25)?25:0));
                int uu = vv + cmm; if (uu >= 25) uu -= 25;
                val = hsw(time_pre[n*1600 + uu*64 + cc]*gt + bt);
            }
            else val = hsw(view_pre[n*19200 + idx - 1600]*gv + bv);
        }
        Ft[ch][lane] = val;
    }
    __syncthreads();
    float acc[16];
    #pragma unroll
    for (int k=0;k<16;k++) acc[k]=0.f;
    const int d0 = w*16;
    #pragma unroll 4
    for (int ch=0; ch<64; ch++){
        float f = Ft[ch][lane];
        #pragma unroll
        for (int dd=0; dd<16; dd++)
            acc[dd] = fmaf(f, Wst[ch][d0+dd], acc[dd]);
    }
    #pragma unroll 1
    for (int dd=0; dd<16; dd++){
        int d = d0 + dd;
        float a = lval ? acc[dd] : 0.f;
        if (lval) sum2_raw[n*20800 + d*325 + l] = a;
        float s = a, q = a*a;
        #pragma unroll
        for (int o=32;o>0;o>>=1){ s += __shfl_down(s,o); q += __shfl_down(q,o); }
        if (lane == 0){
            int b = n*6 + lc;
            chan_part[b*128 + d*2]   = s;
            chan_part[b*128 + d*2+1] = q;
        }
    }
}

// K4: per-channel BN stats.
__global__ void k4_chanstats(const float* __restrict__ chan_part, float* __restrict__ chan_stats)
{
    int d = threadIdx.x;
    float S=0.f, Q=0.f;
    for (int b=0;b<384;b++){ S += chan_part[b*128 + d*2]; Q += chan_part[b*128 + d*2+1]; }
    float m = S/20800.f;
    float var = fmaxf(Q/20800.f - m*m, 0.f);
    chan_stats[d*2] = m;
    chan_stats[d*2+1] = rsqrtf(var + EPS);
}

// K5: xbar partials over 16-n groups (grid 82 x 4).
__global__ __launch_bounds__(256) void k5_xbar(
    const float* __restrict__ sum2_raw, const float* __restrict__ chan_stats,
    const float* __restrict__ g_s, const float* __restrict__ be_s,
    float* __restrict__ xbar_part)
{
    int g = blockIdx.x*256 + threadIdx.x;
    if (g >= 20800) return;
    int d = g / 325;
    float m = chan_stats[d*2], istd = chan_stats[d*2+1];
    float ga = g_s[d]*istd, bb = be_s[d] - m*ga;
    float acc = 0.f;
    int n0 = blockIdx.y*16;
    for (int n=n0;n<n0+16;n++) acc += hsw(sum2_raw[n*20800 + g]*ga + bb);
    xbar_part[blockIdx.y*20800 + g] = acc;
}

// K6: gates (sums 4 xbar partials). l<300 -> x_time (sigmoid); else scale[v][c].
__global__ __launch_bounds__(64) void k6_gates(
    const float* __restrict__ xbar_part, const float* __restrict__ W2t,
    const float* __restrict__ b2t, const float* __restrict__ W2v,
    const float* __restrict__ b2v, float* __restrict__ out_time,
    float* __restrict__ scale_vc)
{
    int l = blockIdx.x, tid = threadIdx.x;
    __shared__ float xb[64];
    int o = tid*325 + l;
    xb[tid] = (xbar_part[o] + xbar_part[20800+o] + xbar_part[41600+o]
             + xbar_part[62400+o]) * (1.f/64.f);
    __syncthreads();
    if (l < 300){
        float acc = b2t[tid];
        for (int d=0; d<64; d++) acc += W2t[tid*64+d]*xb[d];
        out_time[tid*300 + l] = sigm(acc);
    } else {
        int v = l - 300;
        float acc = b2v[tid];
        for (int d=0; d<64; d++) acc += W2v[tid*64+d]*xb[d];
        scale_vc[v*64 + tid] = tanhf(sigm(acc)) + 1.f;
    }
}

// K7 v5: fused gather+GEMM + y write + column-stat bins. TCH=6 -> 31.8KB LDS
// -> 5 blocks/CU. float2 staging (tile base only 8B-aligned at odd tc).
__global__ __launch_bounds__(256) void k7_mfma(
    const float* __restrict__ x0, const float* __restrict__ scale_vc,
    const float* __restrict__ Lw, __hip_bfloat16* __restrict__ y,
    float* __restrict__ col_part)
{
    const int tc = blockIdx.x, n = blockIdx.y, t0 = tc*6;
    const int tid = threadIdx.x;
    __shared__ __hip_bfloat16 lx3[150*68];       // 20400 B (x in, y out)
    __shared__ __hip_bfloat16 Bs[64*64];         //  8192 B
    __shared__ __hip_bfloat16 scb[25*65];        //  3250 B
    for (int i = tid; i < 1600; i += 256){
        int v = i>>6, cl = i&63;
        scb[v*65 + cl] = __float2bfloat16(scale_vc[i]);
    }
    for (int i = tid; i < 4096; i += 256){
        int d = i>>6, cc = i&63;
        int sw = (((cc>>3) ^ (d&7))<<3) + (cc&7);
        Bs[d*64 + sw] = __float2bfloat16(Lw[cc*64 + d]);
    }
    __syncthreads();
    const float* xb = x0 + n*480000 + t0*25;
    // stage: 64 c-rows x 150 cols, float2 per thread
    for (int i = tid; i < 4800; i += 256){
        int c = i/75, c2 = i - c*75;
        float2 f = *reinterpret_cast<const float2*>(xb + c*7500 + c2*2);
        float vals[2] = {f.x, f.y};
        const int cm = c - ((c>=50)?50:((c>=25)?25:0));
        int col0 = c2*2;
        #pragma unroll
        for (int j=0;j<2;j++){
            int col = col0 + j;
            int tt = col/25;
            int u  = col - tt*25;
            int v  = u - cm; if (v < 0) v += 25;
            float s = __bfloat162float(scb[v*65 + c]);
            lx3[(tt*25+v)*68 + c] = __float2bfloat16(vals[j]*s);
        }
    }
    __syncthreads();
    const int wave = tid>>6, lane = tid&63;
    const int lrow = lane&15, lk = lane>>4;
    bf16x8 bfr[4][2];
    #pragma unroll
    for (int nt=0;nt<4;nt++)
      #pragma unroll
      for (int ks=0;ks<2;ks++){
          int kc = ks*4 + lk, d = nt*16 + lrow;
          bfr[nt][ks] = *reinterpret_cast<const bf16x8*>(&Bs[d*64 + ((kc ^ (d&7))<<3)]);
      }
    __hip_bfloat16* yb = y + (size_t)((n*300 + t0)*25)*64;
    for (int q=0; q<3; q++){
        int mt = wave + 4*q;          // 150 rows -> 10 row-tiles
        if (mt >= 10) break;
        int r0 = mt*16 + lrow;
        int r = (r0 < 150) ? r0 : 149;
        bf16x8 afr[2];
        #pragma unroll
        for (int ks=0;ks<2;ks++){
            int c0 = (ks*4 + lk)*8;
            union { bf16x4 h[2]; bf16x8 v8; } u;
            u.h[0] = *reinterpret_cast<const bf16x4*>(&lx3[r*68 + c0]);
            u.h[1] = *reinterpret_cast<const bf16x4*>(&lx3[r*68 + c0 + 4]);
            afr[ks] = u.v8;
        }
        f32x4 acc[4];
        #pragma unroll
        for (int nt=0;nt<4;nt++) acc[nt] = (f32x4){0.f,0.f,0.f,0.f};
        #pragma unroll
        for (int nt=0;nt<4;nt++)
          #pragma unroll
          for (int ks=0;ks<2;ks++)
            acc[nt] = __builtin_amdgcn_mfma_f32_16x16x32_bf16(afr[ks], bfr[nt][ks], acc[nt], 0, 0, 0);
        int rwb = mt*16 + lk*4;
        #pragma unroll
        for (int nt=0;nt<4;nt++){
            int col = nt*16 + lrow;
            #pragma unroll
            for (int j=0;j<4;j++){
                int rw = rwb + j;
                if (rw < 150){
                    __hip_bfloat16 hv = __float2bfloat16(acc[nt][j]);
                    yb[rw*64 + col] = hv;
                    lx3[rw*68 + col] = hv;   // wave-private stripe: no race
                }
            }
        }
    }
    __syncthreads();
    // bin pass: per-block (sum,sumsq) for each column bin = v*64+d over 6 t's
    float* cp = col_part + (size_t)(n*50 + tc)*3200;
    #pragma unroll
    for (int p=0;p<7;p++){
        int bin = tid + 256*p;
        if (bin < 1600){
            int v = bin>>6, d = bin&63;
            float s = 0.f, qq = 0.f;
            #pragma unroll
            for (int tt=0;tt<6;tt++){
                float val = __bfloat162float(lx3[(tt*25+v)*68 + d]);
                s += val; qq += val*val;
            }
            *reinterpret_cast<float2*>(&cp[bin*2]) = make_float2(s, qq);
        }
    }
}

// K8b: reduce 3200 block-partials per column AND write colAB directly
// (shift_out inverse analytic: for column s, j = ((s>>6)+(s&63))%25*64+(s&63)).
__global__ __launch_bounds__(256) void k8b_colAB(
    const float* __restrict__ col_part, const float* __restrict__ g_bn,
    const float* __restrict__ be_bn, float2* __restrict__ colAB)
{
    const int j = blockIdx.x, tid = threadIdx.x;   // j: 4-col chunk, 0..399
    float acc[8] = {0.f,0.f,0.f,0.f,0.f,0.f,0.f,0.f};
    for (int it=0; it<13; ++it){
        int b = tid + 256*it;
        if (b < 3200){
            const float* cp = col_part + (size_t)b*3200 + j*8;
            float4 a = *reinterpret_cast<const float4*>(cp);
            float4 c = *reinterpret_cast<const float4*>(cp+4);
            acc[0]+=a.x; acc[1]+=a.y; acc[2]+=a.z; acc[3]+=a.w;
            acc[4]+=c.x; acc[5]+=c.y; acc[6]+=c.z; acc[7]+=c.w;
        }
    }
    #pragma unroll
    for (int e=0;e<8;e++){
        #pragma unroll
        for (int o=32;o>0;o>>=1) acc[e] += __shfl_down(acc[e], o);
    }
    __shared__ float red[4][8];
    if ((tid&63)==0){
        #pragma unroll
        for (int e=0;e<8;e++) red[tid>>6][e] = acc[e];
    }
    __syncthreads();
    if (tid < 4){
        float S = red[0][2*tid]  +red[1][2*tid]  +red[2][2*tid]  +red[3][2*tid];
        float Q = red[0][2*tid+1]+red[1][2*tid+1]+red[2][2*tid+1]+red[3][2*tid+1];
        float m = S/19200.f;
        float var = fmaxf(Q/19200.f - m*m, 0.f);
        float istd = rsqrtf(var + EPS);
        int s2 = j*4 + tid;
        int d = s2 & 63;
        int vj = ((s2>>6) + d) % 25;
        int jj = vj*64 + d;
        float A = istd * g_bn[jj];
        float B = be_bn[jj] - m*A;
        colAB[s2] = make_float2(A, B);
    }
}

// K9 v5: permute-at-staging, ysp in bf16 (13.3KB LDS -> 8 blocks/CU).
// Stores bf16(A*y+B) with per-row rotation idx=(rem+4d)%104; reads 4 bf16 (8B).
__global__ __launch_bounds__(256) void k9_final(
    const float* __restrict__ x0, const __hip_bfloat16* __restrict__ y,
    const float2* __restrict__ colAB, float* __restrict__ out)
{
    const int tc = blockIdx.x, n = blockIdx.y, t0 = tc*4;
    const int tid = threadIdx.x;
    __shared__ __hip_bfloat16 ysp[64*104];   // 13312 B, [d][(rem+4d)%104]
    const __hip_bfloat16* yb = y + (n*300 + t0)*1600;
    for (int i = tid; i < 1600; i += 256){
        int tt = i / 400;
        int q  = i - tt*400;
        int col0 = q*4;
        uint2 u = *reinterpret_cast<const uint2*>(yb + tt*1600 + col0);
        float4 ab01 = *reinterpret_cast<const float4*>(&colAB[col0]);
        float4 ab23 = *reinterpret_cast<const float4*>(&colAB[col0+2]);
        float yv0 = __uint_as_float(u.x << 16);
        float yv1 = __uint_as_float(u.x & 0xffff0000u);
        float yv2 = __uint_as_float(u.y << 16);
        float yv3 = __uint_as_float(u.y & 0xffff0000u);
        int m = col0 >> 6, d0 = col0 & 63;
        int vv = (m + d0) % 25;
        float vals[4] = { fmaf(yv0, ab01.x, ab01.y), fmaf(yv1, ab01.z, ab01.w),
                          fmaf(yv2, ab23.x, ab23.y), fmaf(yv3, ab23.z, ab23.w) };
        int base = tt*25;
        #pragma unroll
        for (int j=0;j<4;j++){
            int v = vv + j; if (v >= 25) v -= 25;
            int d = d0 + j;
            int idx = base + v + 4*d;
            idx -= (idx >= 208) ? 208 : 0;
            idx -= (idx >= 104) ? 104 : 0;
            ysp[d*104 + idx] = __float2bfloat16(vals[j]);
        }
    }
    __syncthreads();
    const int base_x = n*480000 + tc*100;
    for (int i = tid; i < 1600; i += 256){
        int d = i/25, ch = i - d*25;
        int rem0 = ch*4;
        int idx0 = rem0 + 4*d;
        idx0 -= (idx0 >= 208) ? 208 : 0;
        idx0 -= (idx0 >= 104) ? 104 : 0;
        int gidx = base_x + d*7500 + rem0;
        float4 xv = *reinterpret_cast<const float4*>(x0 + gidx);
        uint2 u = *reinterpret_cast<const uint2*>(&ysp[d*104 + idx0]);
        float yv0 = __uint_as_float(u.x << 16);
        float yv1 = __uint_as_float(u.x & 0xffff0000u);
        float yv2 = __uint_as_float(u.y << 16);
        float yv3 = __uint_as_float(u.y & 0xffff0000u);
        float4 ov;
        ov.x = fmaxf(yv0 + xv.x, 0.f);
        ov.y = fmaxf(yv1 + xv.y, 0.f);
        ov.z = fmaxf(yv2 + xv.z, 0.f);
        ov.w = fmaxf(yv3 + xv.w, 0.f);
        *reinterpret_cast<float4*>(out + gidx) = ov;
    }
}

extern "C" void kernel_launch(void* const* d_in, const int* in_sizes, int n_in,
                              void* d_out, int out_size, void* d_ws, size_t ws_size,
                              hipStream_t stream)
{
    const float* x0       = (const float*)d_in[0];
    const float* Wv       = (const float*)d_in[3];
    const float* g_v      = (const float*)d_in[5];
    const float* be_v     = (const float*)d_in[6];
    const float* Wt       = (const float*)d_in[7];
    const float* g_t      = (const float*)d_in[9];
    const float* be_t     = (const float*)d_in[10];
    const float* Ws       = (const float*)d_in[11];
    const float* g_s      = (const float*)d_in[13];
    const float* be_s     = (const float*)d_in[14];
    const float* W2t      = (const float*)d_in[15];
    const float* b2t      = (const float*)d_in[16];
    const float* W2v      = (const float*)d_in[17];
    const float* b2v      = (const float*)d_in[18];
    const float* Lw       = (const float*)d_in[19];
    const float* g_bn     = (const float*)d_in[21];
    const float* be_bn    = (const float*)d_in[22];
    // shift_in/shift_out are analytic rotations — not read on device.

    float* ws = (float*)d_ws;
    // Region A (ws+0 .. 15,360,000 floats): k1..k6 scratch, ALL dead by k7,
    // then k7 overwrites it with y (30.72M bf16 = 15.36M floats).
    float* view_pre  = ws;                  // 1,228,800   (k1 -> k3)
    float* t0_part   = ws + 1228800;        // 5,120,000   (k1 -> k2a)
    float* time_pre  = ws + 6348800;        //   102,400   (k2a -> k3)
    float* view_part = ws + 6451200;        //     6,400   (k1 -> k2b)
    float* tstat_part= ws + 6457600;        //       800   (k2a -> k2b)
    float* fin       = ws + 6458400;        //         8   (k2b -> k3)
    float* sum2_raw  = ws + 6458408;        // 1,331,200   (k3 -> k5)
    float* chan_part = ws + 7789608;        //    49,152   (k3 -> k4)
    float* chan_stats= ws + 7838760;        //       128   (k4 -> k5)
    float* xbar_part = ws + 7838888;        //    83,200   (k5 -> k6)
    __hip_bfloat16* y = (__hip_bfloat16*)ws; // k7 output over region A
    // Region B (persistent past k7):
    float* scale_vc  = ws + 15360000;       //     1,600   (k6 -> k7)
    float* col_part  = ws + 15361600;       // 10,240,000  (k7 -> k8b)
    float2* colAB    = (float2*)(ws + 25601600); // 3,200 floats (k8b -> k9)

    float* out      = (float*)d_out;
    float* out_time = out + 30720000;

    k1_viewtime   <<<dim3(50,64), 256, 0, stream>>>(x0, Wv, Wt, view_pre, t0_part, view_part);
    k2a_timereduce<<<400, 256, 0, stream>>>(t0_part, time_pre, tstat_part);
    k2b_finstats  <<<1, 256, 0, stream>>>(view_part, tstat_part, fin);
    k3_conv       <<<dim3(6,64), 256, 0, stream>>>(time_pre, view_pre, fin, Ws, g_t, be_t, g_v, be_v, sum2_raw, chan_part);
    k4_chanstats  <<<1, 64, 0, stream>>>(chan_part, chan_stats);
    k5_xbar       <<<dim3(82,4), 256, 0, stream>>>(sum2_raw, chan_stats, g_s, be_s, xbar_part);
    k6_gates      <<<325, 64, 0, stream>>>(xbar_part, W2t, b2t, W2v, b2v, out_time, scale_vc);
    k7_mfma       <<<dim3(50,64), 256, 0, stream>>>(x0, scale_vc, Lw, y, col_part);
    k8b_colAB     <<<400, 256, 0, stream>>>(col_part, g_bn, be_bn, colAB);
    k9_final      <<<dim3(75,64), 256, 0, stream>>>(x0, y, colAB, out);
}

// Round 13
// 219.549 us; speedup vs baseline: 1.1545x; 1.1545x over previous
//
#include <hip/hip_runtime.h>
#include <hip/hip_bf16.h>

#define EPS 1e-5f

typedef __bf16 bf16x8 __attribute__((ext_vector_type(8)));
typedef __bf16 bf16x4 __attribute__((ext_vector_type(4)));
typedef float f32x4 __attribute__((ext_vector_type(4)));

__device__ __forceinline__ float hsw(float x){
    float t = fminf(fmaxf(x + 3.f, 0.f), 6.f);
    return x * t * (1.f/6.f);
}
__device__ __forceinline__ float sigm(float x){ return 1.f/(1.f + expf(-x)); }

// shift_in analytically: s = 64*((v+c)%25)+c -> x[n,c,t,v] = x0[n,c,t,(v+c)%25].
// K1: TCH=6, 8 blocks/CU, coalesced t0_part stores ([u*64+c] layout).
__global__ __launch_bounds__(256, 8) void k1_viewtime(
    const float* __restrict__ x0, const float* __restrict__ Wv,
    const float* __restrict__ Wt, float* __restrict__ view_pre,
    float* __restrict__ t0_part, float* __restrict__ view_part)
{
    const int tc = blockIdx.x, n = blockIdx.y, t0 = tc*6;
    const int tid = threadIdx.x;
    __shared__ alignas(16) unsigned char smem[64*154*2];   // 19712 B
    __shared__ float rs[8];
    __shared__ float WvL[32];
    __hip_bfloat16* lx = (__hip_bfloat16*)smem;   // [c][tt*25+u], stride 154 (77 dw, odd)
    float* red = (float*)smem;                    // [ug*64+c][7] after lx dead
    if (tid < 25) WvL[tid] = Wv[tid];
    const float* xb = x0 + n*480000 + t0*25;
    for (int i = tid; i < 4800; i += 256){
        int row = i/75, c2 = i - row*75;
        float2 f = *reinterpret_cast<const float2*>(xb + row*7500 + c2*2);
        union { unsigned u; __hip_bfloat16 h[2]; } pk;
        pk.h[0]=__float2bfloat16(f.x); pk.h[1]=__float2bfloat16(f.y);
        *reinterpret_cast<unsigned*>(&lx[row*154 + c2*2]) = pk.u;
    }
    float wt[6];
    #pragma unroll
    for (int tt=0;tt<6;tt++) wt[tt] = Wt[t0+tt];
    __syncthreads();
    const int c = tid & 63, ug = tid >> 6;
    const int cm = c - ((c>=50)?50:((c>=25)?25:0));
    float vacc[6] = {0.f,0.f,0.f,0.f,0.f,0.f};
    for (int k=0;k<7;k++){
        int u = ug + 4*k;
        if (u < 25){
            int mm = u - cm; if (mm < 0) mm += 25;
            float wv = WvL[mm];
            int base = c*154 + u;
            float tacc = 0.f;
            #pragma unroll
            for (int tt=0;tt<6;tt++){
                float val = __bfloat162float(lx[base + tt*25]);
                tacc += wt[tt]*val;
                vacc[tt] += wv*val;
            }
            t0_part[(n*50+tc)*1600 + u*64 + c] = tacc;
        }
    }
    __syncthreads();
    #pragma unroll
    for (int tt=0;tt<6;tt++) red[(ug*64+c)*7 + tt] = vacc[tt];
    __syncthreads();
    float vs=0.f, vq=0.f;
    for (int i = tid; i < 384; i += 256){
        int tt = i>>6, c2 = i&63;
        float tot = red[(0*64+c2)*7+tt]+red[(1*64+c2)*7+tt]
                  + red[(2*64+c2)*7+tt]+red[(3*64+c2)*7+tt];
        view_pre[n*19200 + c2*300 + t0+tt] = tot;
        vs += tot; vq += tot*tot;
    }
    #pragma unroll
    for (int o=32;o>0;o>>=1){ vs += __shfl_down(vs,o); vq += __shfl_down(vq,o); }
    if ((tid&63)==0){ rs[(tid>>6)*2]=vs; rs[(tid>>6)*2+1]=vq; }
    __syncthreads();
    if (tid==0){
        view_part[(n*50+tc)*2]   = rs[0]+rs[2]+rs[4]+rs[6];
        view_part[(n*50+tc)*2+1] = rs[1]+rs[3]+rs[5]+rs[7];
    }
}

// K2a: reduce T0 partials over 50 chunks -> time_pre [n][u*64+c]; stat partials.
__global__ __launch_bounds__(256) void k2a_timereduce(
    const float* __restrict__ t0_part, float* __restrict__ time_pre,
    float* __restrict__ tstat_part)
{
    int g = blockIdx.x*256 + threadIdx.x;   // [0, 102400)
    int n = g / 1600, r = g % 1600;
    float s = 0.f;
    for (int tc=0; tc<50; tc++) s += t0_part[(n*50+tc)*1600 + r];
    time_pre[g] = s;
    float a = s, b = s*s;
    __shared__ float ls[8];
    #pragma unroll
    for (int o=32;o>0;o>>=1){ a += __shfl_down(a,o); b += __shfl_down(b,o); }
    int wid = threadIdx.x >> 6;
    if ((threadIdx.x & 63) == 0){ ls[wid*2] = a; ls[wid*2+1] = b; }
    __syncthreads();
    if (threadIdx.x == 0){
        tstat_part[blockIdx.x*2]   = ls[0]+ls[2]+ls[4]+ls[6];
        tstat_part[blockIdx.x*2+1] = ls[1]+ls[3]+ls[5]+ls[7];
    }
}

// K2b: final scalar BN stats for view/time branches.
__global__ __launch_bounds__(256) void k2b_finstats(
    const float* __restrict__ view_part, const float* __restrict__ tstat_part,
    float* __restrict__ fin)
{
    float acc[4] = {0.f,0.f,0.f,0.f};
    for (int i=threadIdx.x; i<3200; i+=256){ acc[0] += view_part[2*i]; acc[1] += view_part[2*i+1]; }
    for (int i=threadIdx.x; i<400;  i+=256){ acc[2] += tstat_part[2*i]; acc[3] += tstat_part[2*i+1]; }
    __shared__ float ls[4][4];
    int wid = threadIdx.x>>6, lane = threadIdx.x&63;
    #pragma unroll
    for (int j=0;j<4;j++){
        float a = acc[j];
        #pragma unroll
        for (int o=32;o>0;o>>=1) a += __shfl_down(a,o);
        if (lane==0) ls[j][wid] = a;
    }
    __syncthreads();
    if (threadIdx.x==0){
        float VS=ls[0][0]+ls[0][1]+ls[0][2]+ls[0][3];
        float VQ=ls[1][0]+ls[1][1]+ls[1][2]+ls[1][3];
        float TS=ls[2][0]+ls[2][1]+ls[2][2]+ls[2][3];
        float TQ=ls[3][0]+ls[3][1]+ls[3][2]+ls[3][3];
        float vm = VS / 1228800.f;
        float vvar = fmaxf(VQ/1228800.f - vm*vm, 0.f);
        float tm = TS / 102400.f;
        float tvar = fmaxf(TQ/102400.f - tm*tm, 0.f);
        fin[0] = vm; fin[1] = rsqrtf(vvar + EPS);
        fin[2] = tm; fin[3] = rsqrtf(tvar + EPS);
    }
}

// K3: sum2_raw[n,d,l] = sum_ch Ws[d,ch]*F(n, ch*325+l); per-d stat partials.
__global__ __launch_bounds__(256) void k3_conv(
    const float* __restrict__ time_pre, const float* __restrict__ view_pre,
    const float* __restrict__ fin, const float* __restrict__ Ws,
    const float* __restrict__ g_t, const float* __restrict__ be_t,
    const float* __restrict__ g_v, const float* __restrict__ be_v,
    float* __restrict__ sum2_raw, float* __restrict__ chan_part)
{
    const int n = blockIdx.y, lc = blockIdx.x;
    const int tid = threadIdx.x, lane = tid & 63, w = tid >> 6;
    const int l = lc*64 + lane;
    __shared__ float Ft[64][64];    // [ch][l-lane]
    __shared__ float Wst[64][64];   // [ch][d]
    for (int i = tid; i < 4096; i += 256){
        int d = i>>6, ch = i&63;
        Wst[ch][d] = Ws[i];
    }
    const float vm = fin[0], vi = fin[1], tm = fin[2], ti = fin[3];
    const float gt = g_t[0]*ti, bt = be_t[0] - tm*g_t[0]*ti;
    const float gv = g_v[0]*vi, bv = be_v[0] - vm*g_v[0]*vi;
    const bool lval = (l < 325);
    for (int k=0;k<16;k++){
        int ch = w + 4*k;
        float val = 0.f;
        if (lval){
            int idx = ch*325 + l;
            if (idx < 1600){
                int cc = idx/25, vv = idx - cc*25;
                int cmm = cc - ((cc>=50)?50:((cc>=25)?25:0));
                int uu = vv + cmm; if (uu >= 25) uu -= 25;
                val = hsw(time_pre[n*1600 + uu*64 + cc]*gt + bt);
            }
            else val = hsw(view_pre[n*19200 + idx - 1600]*gv + bv);
        }
        Ft[ch][lane] = val;
    }
    __syncthreads();
    float acc[16];
    #pragma unroll
    for (int k=0;k<16;k++) acc[k]=0.f;
    const int d0 = w*16;
    #pragma unroll 4
    for (int ch=0; ch<64; ch++){
        float f = Ft[ch][lane];
        #pragma unroll
        for (int dd=0; dd<16; dd++)
            acc[dd] = fmaf(f, Wst[ch][d0+dd], acc[dd]);
    }
    #pragma unroll 1
    for (int dd=0; dd<16; dd++){
        int d = d0 + dd;
        float a = lval ? acc[dd] : 0.f;
        if (lval) sum2_raw[n*20800 + d*325 + l] = a;
        float s = a, q = a*a;
        #pragma unroll
        for (int o=32;o>0;o>>=1){ s += __shfl_down(s,o); q += __shfl_down(q,o); }
        if (lane == 0){
            int b = n*6 + lc;
            chan_part[b*128 + d*2]   = s;
            chan_part[b*128 + d*2+1] = q;
        }
    }
}

// K4: per-channel BN stats.
__global__ void k4_chanstats(const float* __restrict__ chan_part, float* __restrict__ chan_stats)
{
    int d = threadIdx.x;
    float S=0.f, Q=0.f;
    for (int b=0;b<384;b++){ S += chan_part[b*128 + d*2]; Q += chan_part[b*128 + d*2+1]; }
    float m = S/20800.f;
    float var = fmaxf(Q/20800.f - m*m, 0.f);
    chan_stats[d*2] = m;
    chan_stats[d*2+1] = rsqrtf(var + EPS);
}

// K5: xbar partials over 16-n groups (grid 82 x 4).
__global__ __launch_bounds__(256) void k5_xbar(
    const float* __restrict__ sum2_raw, const float* __restrict__ chan_stats,
    const float* __restrict__ g_s, const float* __restrict__ be_s,
    float* __restrict__ xbar_part)
{
    int g = blockIdx.x*256 + threadIdx.x;
    if (g >= 20800) return;
    int d = g / 325;
    float m = chan_stats[d*2], istd = chan_stats[d*2+1];
    float ga = g_s[d]*istd, bb = be_s[d] - m*ga;
    float acc = 0.f;
    int n0 = blockIdx.y*16;
    for (int n=n0;n<n0+16;n++) acc += hsw(sum2_raw[n*20800 + g]*ga + bb);
    xbar_part[blockIdx.y*20800 + g] = acc;
}

// K6: gates (sums 4 xbar partials). l<300 -> x_time (sigmoid); else scale[v][c].
__global__ __launch_bounds__(64) void k6_gates(
    const float* __restrict__ xbar_part, const float* __restrict__ W2t,
    const float* __restrict__ b2t, const float* __restrict__ W2v,
    const float* __restrict__ b2v, float* __restrict__ out_time,
    float* __restrict__ scale_vc)
{
    int l = blockIdx.x, tid = threadIdx.x;
    __shared__ float xb[64];
    int o = tid*325 + l;
    xb[tid] = (xbar_part[o] + xbar_part[20800+o] + xbar_part[41600+o]
             + xbar_part[62400+o]) * (1.f/64.f);
    __syncthreads();
    if (l < 300){
        float acc = b2t[tid];
        for (int d=0; d<64; d++) acc += W2t[tid*64+d]*xb[d];
        out_time[tid*300 + l] = sigm(acc);
    } else {
        int v = l - 300;
        float acc = b2v[tid];
        for (int d=0; d<64; d++) acc += W2v[tid*64+d]*xb[d];
        scale_vc[v*64 + tid] = tanhf(sigm(acc)) + 1.f;
    }
}

// K7 v4 (R10): fused gather+GEMM + y write + column-stat bins. TCH=12.
__global__ __launch_bounds__(256) void k7_mfma(
    const float* __restrict__ x0, const float* __restrict__ scale_vc,
    const float* __restrict__ Lw, __hip_bfloat16* __restrict__ y,
    float* __restrict__ col_part)
{
    const int tc = blockIdx.x, n = blockIdx.y, t0 = tc*12;
    const int tid = threadIdx.x;
    __shared__ __hip_bfloat16 lx3[300*68];       // 40800 B (x in, y out)
    __shared__ __hip_bfloat16 Bs[64*64];         //  8192 B
    __shared__ __hip_bfloat16 scb[25*65];        //  3250 B
    for (int i = tid; i < 1600; i += 256){
        int v = i>>6, cl = i&63;
        scb[v*65 + cl] = __float2bfloat16(scale_vc[i]);
    }
    for (int i = tid; i < 4096; i += 256){
        int d = i>>6, cc = i&63;
        int sw = (((cc>>3) ^ (d&7))<<3) + (cc&7);
        Bs[d*64 + sw] = __float2bfloat16(Lw[cc*64 + d]);
    }
    __syncthreads();
    const float* xb = x0 + n*480000 + t0*25;
    for (int i = tid; i < 4800; i += 256){
        int c = i/75, c4 = i - c*75;
        float4 f = *reinterpret_cast<const float4*>(xb + c*7500 + c4*4);
        float vals[4] = {f.x, f.y, f.z, f.w};
        const int cm = c - ((c>=50)?50:((c>=25)?25:0));
        int col0 = c4*4;
        #pragma unroll
        for (int j=0;j<4;j++){
            int col = col0 + j;
            int tt = col/25;
            int u  = col - tt*25;
            int v  = u - cm; if (v < 0) v += 25;
            float s = __bfloat162float(scb[v*65 + c]);
            lx3[(tt*25+v)*68 + c] = __float2bfloat16(vals[j]*s);
        }
    }
    __syncthreads();
    const int wave = tid>>6, lane = tid&63;
    const int lrow = lane&15, lk = lane>>4;
    bf16x8 bfr[4][2];
    #pragma unroll
    for (int nt=0;nt<4;nt++)
      #pragma unroll
      for (int ks=0;ks<2;ks++){
          int kc = ks*4 + lk, d = nt*16 + lrow;
          bfr[nt][ks] = *reinterpret_cast<const bf16x8*>(&Bs[d*64 + ((kc ^ (d&7))<<3)]);
      }
    __hip_bfloat16* yb = y + (size_t)((n*300 + t0)*25)*64;
    for (int q=0; q<5; q++){
        int mt = wave + 4*q;
        if (mt >= 19) break;
        int r0 = mt*16 + lrow;
        int r = (r0 < 300) ? r0 : 299;
        bf16x8 afr[2];
        #pragma unroll
        for (int ks=0;ks<2;ks++){
            int c0 = (ks*4 + lk)*8;
            union { bf16x4 h[2]; bf16x8 v8; } u;
            u.h[0] = *reinterpret_cast<const bf16x4*>(&lx3[r*68 + c0]);
            u.h[1] = *reinterpret_cast<const bf16x4*>(&lx3[r*68 + c0 + 4]);
            afr[ks] = u.v8;
        }
        f32x4 acc[4];
        #pragma unroll
        for (int nt=0;nt<4;nt++) acc[nt] = (f32x4){0.f,0.f,0.f,0.f};
        #pragma unroll
        for (int nt=0;nt<4;nt++)
          #pragma unroll
          for (int ks=0;ks<2;ks++)
            acc[nt] = __builtin_amdgcn_mfma_f32_16x16x32_bf16(afr[ks], bfr[nt][ks], acc[nt], 0, 0, 0);
        int rwb = mt*16 + lk*4;
        #pragma unroll
        for (int nt=0;nt<4;nt++){
            int col = nt*16 + lrow;
            #pragma unroll
            for (int j=0;j<4;j++){
                int rw = rwb + j;
                if (rw < 300){
                    __hip_bfloat16 hv = __float2bfloat16(acc[nt][j]);
                    yb[rw*64 + col] = hv;
                    lx3[rw*68 + col] = hv;   // wave-private stripe: no race
                }
            }
        }
    }
    __syncthreads();
    // bin pass: per-block (sum,sumsq) for each column bin = v*64+d
    float* cp = col_part + (size_t)(n*25 + tc)*3200;
    #pragma unroll
    for (int p=0;p<7;p++){
        int bin = tid + 256*p;
        if (bin < 1600){
            int v = bin>>6, d = bin&63;
            float s = 0.f, qq = 0.f;
            #pragma unroll
            for (int tt=0;tt<12;tt++){
                float val = __bfloat162float(lx3[(tt*25+v)*68 + d]);
                s += val; qq += val*val;
            }
            *reinterpret_cast<float2*>(&cp[bin*2]) = make_float2(s, qq);
        }
    }
}

// K8b: reduce 1600 block-partials per column AND write colAB directly
// (shift_out inverse analytic: for column s, j = ((s>>6)+(s&63))%25*64+(s&63)).
__global__ __launch_bounds__(256) void k8b_colAB(
    const float* __restrict__ col_part, const float* __restrict__ g_bn,
    const float* __restrict__ be_bn, float2* __restrict__ colAB)
{
    const int j = blockIdx.x, tid = threadIdx.x;   // j: 4-col chunk, 0..399
    float acc[8] = {0.f,0.f,0.f,0.f,0.f,0.f,0.f,0.f};
    for (int it=0; it<7; ++it){
        int b = tid + 256*it;
        if (b < 1600){
            const float* cp = col_part + (size_t)b*3200 + j*8;
            float4 a = *reinterpret_cast<const float4*>(cp);
            float4 c = *reinterpret_cast<const float4*>(cp+4);
            acc[0]+=a.x; acc[1]+=a.y; acc[2]+=a.z; acc[3]+=a.w;
            acc[4]+=c.x; acc[5]+=c.y; acc[6]+=c.z; acc[7]+=c.w;
        }
    }
    #pragma unroll
    for (int e=0;e<8;e++){
        #pragma unroll
        for (int o=32;o>0;o>>=1) acc[e] += __shfl_down(acc[e], o);
    }
    __shared__ float red[4][8];
    if ((tid&63)==0){
        #pragma unroll
        for (int e=0;e<8;e++) red[tid>>6][e] = acc[e];
    }
    __syncthreads();
    if (tid < 4){
        float S = red[0][2*tid]  +red[1][2*tid]  +red[2][2*tid]  +red[3][2*tid];
        float Q = red[0][2*tid+1]+red[1][2*tid+1]+red[2][2*tid+1]+red[3][2*tid+1];
        float m = S/19200.f;
        float var = fmaxf(Q/19200.f - m*m, 0.f);
        float istd = rsqrtf(var + EPS);
        int s2 = j*4 + tid;
        int d = s2 & 63;
        int vj = ((s2>>6) + d) % 25;
        int jj = vj*64 + d;
        float A = istd * g_bn[jj];
        float B = be_bn[jj] - m*A;
        colAB[s2] = make_float2(A, B);
    }
}

// K9 v5: permute-at-staging, ysp in bf16 (13.3KB LDS -> 8 blocks/CU).
// Stores bf16(A*y+B) with per-row rotation idx=(rem+4d)%104; reads 4 bf16 (8B).
__global__ __launch_bounds__(256) void k9_final(
    const float* __restrict__ x0, const __hip_bfloat16* __restrict__ y,
    const float2* __restrict__ colAB, float* __restrict__ out)
{
    const int tc = blockIdx.x, n = blockIdx.y, t0 = tc*4;
    const int tid = threadIdx.x;
    __shared__ __hip_bfloat16 ysp[64*104];   // 13312 B, [d][(rem+4d)%104]
    const __hip_bfloat16* yb = y + (n*300 + t0)*1600;
    for (int i = tid; i < 1600; i += 256){
        int tt = i / 400;
        int q  = i - tt*400;
        int col0 = q*4;
        uint2 u = *reinterpret_cast<const uint2*>(yb + tt*1600 + col0);
        float4 ab01 = *reinterpret_cast<const float4*>(&colAB[col0]);
        float4 ab23 = *reinterpret_cast<const float4*>(&colAB[col0+2]);
        float yv0 = __uint_as_float(u.x << 16);
        float yv1 = __uint_as_float(u.x & 0xffff0000u);
        float yv2 = __uint_as_float(u.y << 16);
        float yv3 = __uint_as_float(u.y & 0xffff0000u);
        int m = col0 >> 6, d0 = col0 & 63;
        int vv = (m + d0) % 25;
        float vals[4] = { fmaf(yv0, ab01.x, ab01.y), fmaf(yv1, ab01.z, ab01.w),
                          fmaf(yv2, ab23.x, ab23.y), fmaf(yv3, ab23.z, ab23.w) };
        int base = tt*25;
        #pragma unroll
        for (int j=0;j<4;j++){
            int v = vv + j; if (v >= 25) v -= 25;
            int d = d0 + j;
            int idx = base + v + 4*d;
            idx -= (idx >= 208) ? 208 : 0;
            idx -= (idx >= 104) ? 104 : 0;
            ysp[d*104 + idx] = __float2bfloat16(vals[j]);
        }
    }
    __syncthreads();
    const int base_x = n*480000 + tc*100;
    for (int i = tid; i < 1600; i += 256){
        int d = i/25, ch = i - d*25;
        int rem0 = ch*4;
        int idx0 = rem0 + 4*d;
        idx0 -= (idx0 >= 208) ? 208 : 0;
        idx0 -= (idx0 >= 104) ? 104 : 0;
        int gidx = base_x + d*7500 + rem0;
        float4 xv = *reinterpret_cast<const float4*>(x0 + gidx);
        uint2 u = *reinterpret_cast<const uint2*>(&ysp[d*104 + idx0]);
        float yv0 = __uint_as_float(u.x << 16);
        float yv1 = __uint_as_float(u.x & 0xffff0000u);
        float yv2 = __uint_as_float(u.y << 16);
        float yv3 = __uint_as_float(u.y & 0xffff0000u);
        float4 ov;
        ov.x = fmaxf(yv0 + xv.x, 0.f);
        ov.y = fmaxf(yv1 + xv.y, 0.f);
        ov.z = fmaxf(yv2 + xv.z, 0.f);
        ov.w = fmaxf(yv3 + xv.w, 0.f);
        *reinterpret_cast<float4*>(out + gidx) = ov;
    }
}

extern "C" void kernel_launch(void* const* d_in, const int* in_sizes, int n_in,
                              void* d_out, int out_size, void* d_ws, size_t ws_size,
                              hipStream_t stream)
{
    const float* x0       = (const float*)d_in[0];
    const float* Wv       = (const float*)d_in[3];
    const float* g_v      = (const float*)d_in[5];
    const float* be_v     = (const float*)d_in[6];
    const float* Wt       = (const float*)d_in[7];
    const float* g_t      = (const float*)d_in[9];
    const float* be_t     = (const float*)d_in[10];
    const float* Ws       = (const float*)d_in[11];
    const float* g_s      = (const float*)d_in[13];
    const float* be_s     = (const float*)d_in[14];
    const float* W2t      = (const float*)d_in[15];
    const float* b2t      = (const float*)d_in[16];
    const float* W2v      = (const float*)d_in[17];
    const float* b2v      = (const float*)d_in[18];
    const float* Lw       = (const float*)d_in[19];
    const float* g_bn     = (const float*)d_in[21];
    const float* be_bn    = (const float*)d_in[22];
    // shift_in/shift_out are analytic rotations — not read on device.

    float* ws = (float*)d_ws;
    // Region A (ws+0 .. 15,360,000 floats): k1..k6 scratch, ALL dead by k7,
    // then k7 overwrites it with y (30.72M bf16 = 15.36M floats).
    float* view_pre  = ws;                  // 1,228,800   (k1 -> k3)
    float* t0_part   = ws + 1228800;        // 5,120,000   (k1 -> k2a)
    float* time_pre  = ws + 6348800;        //   102,400   (k2a -> k3)
    float* view_part = ws + 6451200;        //     6,400   (k1 -> k2b)
    float* tstat_part= ws + 6457600;        //       800   (k2a -> k2b)
    float* fin       = ws + 6458400;        //         8   (k2b -> k3)
    float* sum2_raw  = ws + 6458408;        // 1,331,200   (k3 -> k5)
    float* chan_part = ws + 7789608;        //    49,152   (k3 -> k4)
    float* chan_stats= ws + 7838760;        //       128   (k4 -> k5)
    float* xbar_part = ws + 7838888;        //    83,200   (k5 -> k6)
    __hip_bfloat16* y = (__hip_bfloat16*)ws; // k7 output over region A
    // Region B (persistent past k7):
    float* scale_vc  = ws + 15360000;       //     1,600   (k6 -> k7)
    float* col_part  = ws + 15361600;       // 5,120,000   (k7 -> k8b)
    float2* colAB    = (float2*)(ws + 20481600); // 3,200 floats (k8b -> k9)

    float* out      = (float*)d_out;
    float* out_time = out + 30720000;

    k1_viewtime   <<<dim3(50,64), 256, 0, stream>>>(x0, Wv, Wt, view_pre, t0_part, view_part);
    k2a_timereduce<<<400, 256, 0, stream>>>(t0_part, time_pre, tstat_part);
    k2b_finstats  <<<1, 256, 0, stream>>>(view_part, tstat_part, fin);
    k3_conv       <<<dim3(6,64), 256, 0, stream>>>(time_pre, view_pre, fin, Ws, g_t, be_t, g_v, be_v, sum2_raw, chan_part);
    k4_chanstats  <<<1, 64, 0, stream>>>(chan_part, chan_stats);
    k5_xbar       <<<dim3(82,4), 256, 0, stream>>>(sum2_raw, chan_stats, g_s, be_s, xbar_part);
    k6_gates      <<<325, 64, 0, stream>>>(xbar_part, W2t, b2t, W2v, b2v, out_time, scale_vc);
    k7_mfma       <<<dim3(25,64), 256, 0, stream>>>(x0, scale_vc, Lw, y, col_part);
    k8b_colAB     <<<400, 256, 0, stream>>>(col_part, g_bn, be_bn, colAB);
    k9_final      <<<dim3(75,64), 256, 0, stream>>>(x0, y, colAB, out);
}

// Round 14
// 217.237 us; speedup vs baseline: 1.1667x; 1.0106x over previous
//
#include <hip/hip_runtime.h>
#include <hip/hip_bf16.h>

#define EPS 1e-5f

typedef __bf16 bf16x8 __attribute__((ext_vector_type(8)));
typedef __bf16 bf16x4 __attribute__((ext_vector_type(4)));
typedef float f32x4 __attribute__((ext_vector_type(4)));

__device__ __forceinline__ float hsw(float x){
    float t = fminf(fmaxf(x + 3.f, 0.f), 6.f);
    return x * t * (1.f/6.f);
}
__device__ __forceinline__ float sigm(float x){ return 1.f/(1.f + expf(-x)); }

// shift_in analytically: s = 64*((v+c)%25)+c -> x[n,c,t,v] = x0[n,c,t,(v+c)%25].
// K1: TCH=6, 8 blocks/CU, coalesced t0_part stores ([u*64+c] layout).
__global__ __launch_bounds__(256, 8) void k1_viewtime(
    const float* __restrict__ x0, const float* __restrict__ Wv,
    const float* __restrict__ Wt, float* __restrict__ view_pre,
    float* __restrict__ t0_part, float* __restrict__ view_part)
{
    const int tc = blockIdx.x, n = blockIdx.y, t0 = tc*6;
    const int tid = threadIdx.x;
    __shared__ alignas(16) unsigned char smem[64*154*2];   // 19712 B
    __shared__ float rs[8];
    __shared__ float WvL[32];
    __hip_bfloat16* lx = (__hip_bfloat16*)smem;   // [c][tt*25+u], stride 154 (77 dw, odd)
    float* red = (float*)smem;                    // [ug*64+c][7] after lx dead
    if (tid < 25) WvL[tid] = Wv[tid];
    const float* xb = x0 + n*480000 + t0*25;
    for (int i = tid; i < 4800; i += 256){
        int row = i/75, c2 = i - row*75;
        float2 f = *reinterpret_cast<const float2*>(xb + row*7500 + c2*2);
        union { unsigned u; __hip_bfloat16 h[2]; } pk;
        pk.h[0]=__float2bfloat16(f.x); pk.h[1]=__float2bfloat16(f.y);
        *reinterpret_cast<unsigned*>(&lx[row*154 + c2*2]) = pk.u;
    }
    float wt[6];
    #pragma unroll
    for (int tt=0;tt<6;tt++) wt[tt] = Wt[t0+tt];
    __syncthreads();
    const int c = tid & 63, ug = tid >> 6;
    const int cm = c - ((c>=50)?50:((c>=25)?25:0));
    float vacc[6] = {0.f,0.f,0.f,0.f,0.f,0.f};
    for (int k=0;k<7;k++){
        int u = ug + 4*k;
        if (u < 25){
            int mm = u - cm; if (mm < 0) mm += 25;
            float wv = WvL[mm];
            int base = c*154 + u;
            float tacc = 0.f;
            #pragma unroll
            for (int tt=0;tt<6;tt++){
                float val = __bfloat162float(lx[base + tt*25]);
                tacc += wt[tt]*val;
                vacc[tt] += wv*val;
            }
            t0_part[(n*50+tc)*1600 + u*64 + c] = tacc;
        }
    }
    __syncthreads();
    #pragma unroll
    for (int tt=0;tt<6;tt++) red[(ug*64+c)*7 + tt] = vacc[tt];
    __syncthreads();
    float vs=0.f, vq=0.f;
    for (int i = tid; i < 384; i += 256){
        int tt = i>>6, c2 = i&63;
        float tot = red[(0*64+c2)*7+tt]+red[(1*64+c2)*7+tt]
                  + red[(2*64+c2)*7+tt]+red[(3*64+c2)*7+tt];
        view_pre[n*19200 + c2*300 + t0+tt] = tot;
        vs += tot; vq += tot*tot;
    }
    #pragma unroll
    for (int o=32;o>0;o>>=1){ vs += __shfl_down(vs,o); vq += __shfl_down(vq,o); }
    if ((tid&63)==0){ rs[(tid>>6)*2]=vs; rs[(tid>>6)*2+1]=vq; }
    __syncthreads();
    if (tid==0){
        view_part[(n*50+tc)*2]   = rs[0]+rs[2]+rs[4]+rs[6];
        view_part[(n*50+tc)*2+1] = rs[1]+rs[3]+rs[5]+rs[7];
    }
}

// K2a v2: float2 per thread (200 blocks); reduce T0 partials over 50 chunks.
__global__ __launch_bounds__(256) void k2a_timereduce(
    const float* __restrict__ t0_part, float* __restrict__ time_pre,
    float* __restrict__ tstat_part)
{
    int g = blockIdx.x*256 + threadIdx.x;   // [0, 51200) element-pairs
    int n = g / 800, rp = g - n*800;
    int r = rp*2;
    float s0 = 0.f, s1 = 0.f;
    const float* tp = t0_part + (size_t)n*80000 + r;
    for (int tc=0; tc<50; tc++){
        float2 f = *reinterpret_cast<const float2*>(tp + tc*1600);
        s0 += f.x; s1 += f.y;
    }
    *reinterpret_cast<float2*>(time_pre + n*1600 + r) = make_float2(s0, s1);
    float a = s0 + s1, b = s0*s0 + s1*s1;
    __shared__ float ls[8];
    #pragma unroll
    for (int o=32;o>0;o>>=1){ a += __shfl_down(a,o); b += __shfl_down(b,o); }
    int wid = threadIdx.x >> 6;
    if ((threadIdx.x & 63) == 0){ ls[wid*2] = a; ls[wid*2+1] = b; }
    __syncthreads();
    if (threadIdx.x == 0){
        tstat_part[blockIdx.x*2]   = ls[0]+ls[2]+ls[4]+ls[6];
        tstat_part[blockIdx.x*2+1] = ls[1]+ls[3]+ls[5]+ls[7];
    }
}

// K3 v2 (k2b fused): each block re-reduces view/tstat partials -> fin, then
// sum2_raw[n,d,l] = sum_ch Ws[d,ch]*F(n, ch*325+l); per-d stat partials.
__global__ __launch_bounds__(256) void k3_conv(
    const float* __restrict__ time_pre, const float* __restrict__ view_pre,
    const float* __restrict__ view_part, const float* __restrict__ tstat_part,
    const float* __restrict__ Ws,
    const float* __restrict__ g_t, const float* __restrict__ be_t,
    const float* __restrict__ g_v, const float* __restrict__ be_v,
    float* __restrict__ sum2_raw, float* __restrict__ chan_part)
{
    const int n = blockIdx.y, lc = blockIdx.x;
    const int tid = threadIdx.x, lane = tid & 63, w = tid >> 6;
    const int l = lc*64 + lane;
    __shared__ float Ft[64][64];    // [ch][l-lane]
    __shared__ float Wst[64][64];   // [ch][d]
    __shared__ float ls[4][4];
    __shared__ float finL[4];
    for (int i = tid; i < 4096; i += 256){
        int d = i>>6, ch = i&63;
        Wst[ch][d] = Ws[i];
    }
    // inline fin reduction (was k2b)
    {
        float acc[4] = {0.f,0.f,0.f,0.f};
        for (int i=tid; i<3200; i+=256){ acc[0] += view_part[2*i]; acc[1] += view_part[2*i+1]; }
        for (int i=tid; i<200;  i+=256){ acc[2] += tstat_part[2*i]; acc[3] += tstat_part[2*i+1]; }
        #pragma unroll
        for (int j=0;j<4;j++){
            float a = acc[j];
            #pragma unroll
            for (int o=32;o>0;o>>=1) a += __shfl_down(a,o);
            if (lane==0) ls[j][w] = a;
        }
        __syncthreads();
        if (tid==0){
            float VS=ls[0][0]+ls[0][1]+ls[0][2]+ls[0][3];
            float VQ=ls[1][0]+ls[1][1]+ls[1][2]+ls[1][3];
            float TS=ls[2][0]+ls[2][1]+ls[2][2]+ls[2][3];
            float TQ=ls[3][0]+ls[3][1]+ls[3][2]+ls[3][3];
            float vm = VS / 1228800.f;
            float vvar = fmaxf(VQ/1228800.f - vm*vm, 0.f);
            float tm = TS / 102400.f;
            float tvar = fmaxf(TQ/102400.f - tm*tm, 0.f);
            finL[0] = vm; finL[1] = rsqrtf(vvar + EPS);
            finL[2] = tm; finL[3] = rsqrtf(tvar + EPS);
        }
        __syncthreads();
    }
    const float vm = finL[0], vi = finL[1], tm = finL[2], ti = finL[3];
    const float gt = g_t[0]*ti, bt = be_t[0] - tm*g_t[0]*ti;
    const float gv = g_v[0]*vi, bv = be_v[0] - vm*g_v[0]*vi;
    const bool lval = (l < 325);
    for (int k=0;k<16;k++){
        int ch = w + 4*k;
        float val = 0.f;
        if (lval){
            int idx = ch*325 + l;
            if (idx < 1600){
                int cc = idx/25, vv = idx - cc*25;
                int cmm = cc - ((cc>=50)?50:((cc>=25)?25:0));
                int uu = vv + cmm; if (uu >= 25) uu -= 25;
                val = hsw(time_pre[n*1600 + uu*64 + cc]*gt + bt);
            }
            else val = hsw(view_pre[n*19200 + idx - 1600]*gv + bv);
        }
        Ft[ch][lane] = val;
    }
    __syncthreads();
    float acc[16];
    #pragma unroll
    for (int k=0;k<16;k++) acc[k]=0.f;
    const int d0 = w*16;
    #pragma unroll 4
    for (int ch=0; ch<64; ch++){
        float f = Ft[ch][lane];
        #pragma unroll
        for (int dd=0; dd<16; dd++)
            acc[dd] = fmaf(f, Wst[ch][d0+dd], acc[dd]);
    }
    #pragma unroll 1
    for (int dd=0; dd<16; dd++){
        int d = d0 + dd;
        float a = lval ? acc[dd] : 0.f;
        if (lval) sum2_raw[n*20800 + d*325 + l] = a;
        float s = a, q = a*a;
        #pragma unroll
        for (int o=32;o>0;o>>=1){ s += __shfl_down(s,o); q += __shfl_down(q,o); }
        if (lane == 0){
            int b = n*6 + lc;
            chan_part[b*128 + d*2]   = s;
            chan_part[b*128 + d*2+1] = q;
        }
    }
}

// K5 v2 (k4 fused): threads 0-63 re-reduce chan_part -> chan stats in LDS,
// then xbar partials over 16-n groups (grid 82 x 4).
__global__ __launch_bounds__(256) void k5_xbar(
    const float* __restrict__ sum2_raw, const float* __restrict__ chan_part,
    const float* __restrict__ g_s, const float* __restrict__ be_s,
    float* __restrict__ xbar_part)
{
    __shared__ float cs[64][2];
    const int tid = threadIdx.x;
    if (tid < 64){
        float S=0.f, Q=0.f;
        for (int b=0;b<384;b++){ S += chan_part[b*128 + tid*2]; Q += chan_part[b*128 + tid*2+1]; }
        float m = S/20800.f;
        float var = fmaxf(Q/20800.f - m*m, 0.f);
        cs[tid][0] = m;
        cs[tid][1] = rsqrtf(var + EPS);
    }
    __syncthreads();
    int g = blockIdx.x*256 + tid;
    if (g >= 20800) return;
    int d = g / 325;
    float m = cs[d][0], istd = cs[d][1];
    float ga = g_s[d]*istd, bb = be_s[d] - m*ga;
    float acc = 0.f;
    int n0 = blockIdx.y*16;
    for (int n=n0;n<n0+16;n++) acc += hsw(sum2_raw[n*20800 + g]*ga + bb);
    xbar_part[blockIdx.y*20800 + g] = acc;
}

// K6: gates (sums 4 xbar partials). l<300 -> x_time (sigmoid); else scale[v][c].
__global__ __launch_bounds__(64) void k6_gates(
    const float* __restrict__ xbar_part, const float* __restrict__ W2t,
    const float* __restrict__ b2t, const float* __restrict__ W2v,
    const float* __restrict__ b2v, float* __restrict__ out_time,
    float* __restrict__ scale_vc)
{
    int l = blockIdx.x, tid = threadIdx.x;
    __shared__ float xb[64];
    int o = tid*325 + l;
    xb[tid] = (xbar_part[o] + xbar_part[20800+o] + xbar_part[41600+o]
             + xbar_part[62400+o]) * (1.f/64.f);
    __syncthreads();
    if (l < 300){
        float acc = b2t[tid];
        for (int d=0; d<64; d++) acc += W2t[tid*64+d]*xb[d];
        out_time[tid*300 + l] = sigm(acc);
    } else {
        int v = l - 300;
        float acc = b2v[tid];
        for (int d=0; d<64; d++) acc += W2v[tid*64+d]*xb[d];
        scale_vc[v*64 + tid] = tanhf(sigm(acc)) + 1.f;
    }
}

// K7 (R10 structure, incremental staging walk): fused gather+GEMM + y write +
// column-stat bins. TCH=12.
__global__ __launch_bounds__(256) void k7_mfma(
    const float* __restrict__ x0, const float* __restrict__ scale_vc,
    const float* __restrict__ Lw, __hip_bfloat16* __restrict__ y,
    float* __restrict__ col_part)
{
    const int tc = blockIdx.x, n = blockIdx.y, t0 = tc*12;
    const int tid = threadIdx.x;
    __shared__ __hip_bfloat16 lx3[300*68];       // 40800 B (x in, y out)
    __shared__ __hip_bfloat16 Bs[64*64];         //  8192 B
    __shared__ __hip_bfloat16 scb[25*65];        //  3250 B
    for (int i = tid; i < 1600; i += 256){
        int v = i>>6, cl = i&63;
        scb[v*65 + cl] = __float2bfloat16(scale_vc[i]);
    }
    for (int i = tid; i < 4096; i += 256){
        int d = i>>6, cc = i&63;
        int sw = (((cc>>3) ^ (d&7))<<3) + (cc&7);
        Bs[d*64 + sw] = __float2bfloat16(Lw[cc*64 + d]);
    }
    __syncthreads();
    const float* xb = x0 + n*480000 + t0*25;
    for (int i = tid; i < 4800; i += 256){
        int c = i/75, c4 = i - c*75;
        float4 f = *reinterpret_cast<const float4*>(xb + c*7500 + c4*4);
        float vals[4] = {f.x, f.y, f.z, f.w};
        const int cm = c - ((c>=50)?50:((c>=25)?25:0));
        const int vwrap = (cm==0) ? 0 : (25-cm);
        int col0 = c4*4;
        int tt = col0/25;
        int u  = col0 - tt*25;
        int tt25 = tt*25;
        int v  = u - cm; if (v < 0) v += 25;
        #pragma unroll
        for (int j=0;j<4;j++){
            float s = __bfloat162float(scb[v*65 + c]);
            lx3[(tt25+v)*68 + c] = __float2bfloat16(vals[j]*s);
            u++;
            if (u == 25){ u = 0; tt25 += 25; v = vwrap; }
            else { v++; if (v == 25) v = 0; }
        }
    }
    __syncthreads();
    const int wave = tid>>6, lane = tid&63;
    const int lrow = lane&15, lk = lane>>4;
    bf16x8 bfr[4][2];
    #pragma unroll
    for (int nt=0;nt<4;nt++)
      #pragma unroll
      for (int ks=0;ks<2;ks++){
          int kc = ks*4 + lk, d = nt*16 + lrow;
          bfr[nt][ks] = *reinterpret_cast<const bf16x8*>(&Bs[d*64 + ((kc ^ (d&7))<<3)]);
      }
    __hip_bfloat16* yb = y + (size_t)((n*300 + t0)*25)*64;
    for (int q=0; q<5; q++){
        int mt = wave + 4*q;
        if (mt >= 19) break;
        int r0 = mt*16 + lrow;
        int r = (r0 < 300) ? r0 : 299;
        bf16x8 afr[2];
        #pragma unroll
        for (int ks=0;ks<2;ks++){
            int c0 = (ks*4 + lk)*8;
            union { bf16x4 h[2]; bf16x8 v8; } u;
            u.h[0] = *reinterpret_cast<const bf16x4*>(&lx3[r*68 + c0]);
            u.h[1] = *reinterpret_cast<const bf16x4*>(&lx3[r*68 + c0 + 4]);
            afr[ks] = u.v8;
        }
        f32x4 acc[4];
        #pragma unroll
        for (int nt=0;nt<4;nt++) acc[nt] = (f32x4){0.f,0.f,0.f,0.f};
        #pragma unroll
        for (int nt=0;nt<4;nt++)
          #pragma unroll
          for (int ks=0;ks<2;ks++)
            acc[nt] = __builtin_amdgcn_mfma_f32_16x16x32_bf16(afr[ks], bfr[nt][ks], acc[nt], 0, 0, 0);
        int rwb = mt*16 + lk*4;
        #pragma unroll
        for (int nt=0;nt<4;nt++){
            int col = nt*16 + lrow;
            #pragma unroll
            for (int j=0;j<4;j++){
                int rw = rwb + j;
                if (rw < 300){
                    __hip_bfloat16 hv = __float2bfloat16(acc[nt][j]);
                    yb[rw*64 + col] = hv;
                    lx3[rw*68 + col] = hv;   // wave-private stripe: no race
                }
            }
        }
    }
    __syncthreads();
    // bin pass: per-block (sum,sumsq) for each column bin = v*64+d
    float* cp = col_part + (size_t)(n*25 + tc)*3200;
    #pragma unroll
    for (int p=0;p<7;p++){
        int bin = tid + 256*p;
        if (bin < 1600){
            int v = bin>>6, d = bin&63;
            float s = 0.f, qq = 0.f;
            #pragma unroll
            for (int tt=0;tt<12;tt++){
                float val = __bfloat162float(lx3[(tt*25+v)*68 + d]);
                s += val; qq += val*val;
            }
            *reinterpret_cast<float2*>(&cp[bin*2]) = make_float2(s, qq);
        }
    }
}

// K8b: reduce 1600 block-partials per column AND write colAB directly
// (shift_out inverse analytic: for column s, j = ((s>>6)+(s&63))%25*64+(s&63)).
__global__ __launch_bounds__(256) void k8b_colAB(
    const float* __restrict__ col_part, const float* __restrict__ g_bn,
    const float* __restrict__ be_bn, float2* __restrict__ colAB)
{
    const int j = blockIdx.x, tid = threadIdx.x;   // j: 4-col chunk, 0..399
    float acc[8] = {0.f,0.f,0.f,0.f,0.f,0.f,0.f,0.f};
    for (int it=0; it<7; ++it){
        int b = tid + 256*it;
        if (b < 1600){
            const float* cp = col_part + (size_t)b*3200 + j*8;
            float4 a = *reinterpret_cast<const float4*>(cp);
            float4 c = *reinterpret_cast<const float4*>(cp+4);
            acc[0]+=a.x; acc[1]+=a.y; acc[2]+=a.z; acc[3]+=a.w;
            acc[4]+=c.x; acc[5]+=c.y; acc[6]+=c.z; acc[7]+=c.w;
        }
    }
    #pragma unroll
    for (int e=0;e<8;e++){
        #pragma unroll
        for (int o=32;o>0;o>>=1) acc[e] += __shfl_down(acc[e], o);
    }
    __shared__ float red[4][8];
    if ((tid&63)==0){
        #pragma unroll
        for (int e=0;e<8;e++) red[tid>>6][e] = acc[e];
    }
    __syncthreads();
    if (tid < 4){
        float S = red[0][2*tid]  +red[1][2*tid]  +red[2][2*tid]  +red[3][2*tid];
        float Q = red[0][2*tid+1]+red[1][2*tid+1]+red[2][2*tid+1]+red[3][2*tid+1];
        float m = S/19200.f;
        float var = fmaxf(Q/19200.f - m*m, 0.f);
        float istd = rsqrtf(var + EPS);
        int s2 = j*4 + tid;
        int d = s2 & 63;
        int vj = ((s2>>6) + d) % 25;
        int jj = vj*64 + d;
        float A = istd * g_bn[jj];
        float B = be_bn[jj] - m*A;
        colAB[s2] = make_float2(A, B);
    }
}

// K9: permute-at-staging, ysp in bf16 (13.3KB LDS).
// Stores bf16(A*y+B) with per-row rotation idx=(rem+4d)%104; reads 4 bf16 (8B).
__global__ __launch_bounds__(256) void k9_final(
    const float* __restrict__ x0, const __hip_bfloat16* __restrict__ y,
    const float2* __restrict__ colAB, float* __restrict__ out)
{
    const int tc = blockIdx.x, n = blockIdx.y, t0 = tc*4;
    const int tid = threadIdx.x;
    __shared__ __hip_bfloat16 ysp[64*104];   // 13312 B, [d][(rem+4d)%104]
    const __hip_bfloat16* yb = y + (n*300 + t0)*1600;
    for (int i = tid; i < 1600; i += 256){
        int tt = i / 400;
        int q  = i - tt*400;
        int col0 = q*4;
        uint2 u = *reinterpret_cast<const uint2*>(yb + tt*1600 + col0);
        float4 ab01 = *reinterpret_cast<const float4*>(&colAB[col0]);
        float4 ab23 = *reinterpret_cast<const float4*>(&colAB[col0+2]);
        float yv0 = __uint_as_float(u.x << 16);
        float yv1 = __uint_as_float(u.x & 0xffff0000u);
        float yv2 = __uint_as_float(u.y << 16);
        float yv3 = __uint_as_float(u.y & 0xffff0000u);
        int m = col0 >> 6, d0 = col0 & 63;
        int vv = (m + d0) % 25;
        float vals[4] = { fmaf(yv0, ab01.x, ab01.y), fmaf(yv1, ab01.z, ab01.w),
                          fmaf(yv2, ab23.x, ab23.y), fmaf(yv3, ab23.z, ab23.w) };
        int base = tt*25;
        #pragma unroll
        for (int j=0;j<4;j++){
            int v = vv + j; if (v >= 25) v -= 25;
            int d = d0 + j;
            int idx = base + v + 4*d;
            idx -= (idx >= 208) ? 208 : 0;
            idx -= (idx >= 104) ? 104 : 0;
            ysp[d*104 + idx] = __float2bfloat16(vals[j]);
        }
    }
    __syncthreads();
    const int base_x = n*480000 + tc*100;
    for (int i = tid; i < 1600; i += 256){
        int d = i/25, ch = i - d*25;
        int rem0 = ch*4;
        int idx0 = rem0 + 4*d;
        idx0 -= (idx0 >= 208) ? 208 : 0;
        idx0 -= (idx0 >= 104) ? 104 : 0;
        int gidx = base_x + d*7500 + rem0;
        float4 xv = *reinterpret_cast<const float4*>(x0 + gidx);
        uint2 u = *reinterpret_cast<const uint2*>(&ysp[d*104 + idx0]);
        float yv0 = __uint_as_float(u.x << 16);
        float yv1 = __uint_as_float(u.x & 0xffff0000u);
        float yv2 = __uint_as_float(u.y << 16);
        float yv3 = __uint_as_float(u.y & 0xffff0000u);
        float4 ov;
        ov.x = fmaxf(yv0 + xv.x, 0.f);
        ov.y = fmaxf(yv1 + xv.y, 0.f);
        ov.z = fmaxf(yv2 + xv.z, 0.f);
        ov.w = fmaxf(yv3 + xv.w, 0.f);
        *reinterpret_cast<float4*>(out + gidx) = ov;
    }
}

extern "C" void kernel_launch(void* const* d_in, const int* in_sizes, int n_in,
                              void* d_out, int out_size, void* d_ws, size_t ws_size,
                              hipStream_t stream)
{
    const float* x0       = (const float*)d_in[0];
    const float* Wv       = (const float*)d_in[3];
    const float* g_v      = (const float*)d_in[5];
    const float* be_v     = (const float*)d_in[6];
    const float* Wt       = (const float*)d_in[7];
    const float* g_t      = (const float*)d_in[9];
    const float* be_t     = (const float*)d_in[10];
    const float* Ws       = (const float*)d_in[11];
    const float* g_s      = (const float*)d_in[13];
    const float* be_s     = (const float*)d_in[14];
    const float* W2t      = (const float*)d_in[15];
    const float* b2t      = (const float*)d_in[16];
    const float* W2v      = (const float*)d_in[17];
    const float* b2v      = (const float*)d_in[18];
    const float* Lw       = (const float*)d_in[19];
    const float* g_bn     = (const float*)d_in[21];
    const float* be_bn    = (const float*)d_in[22];
    // shift_in/shift_out are analytic rotations — not read on device.

    float* ws = (float*)d_ws;
    // Region A (ws+0 .. 15,360,000 floats): k1..k6 scratch, ALL dead by k7,
    // then k7 overwrites it with y (30.72M bf16 = 15.36M floats).
    float* view_pre  = ws;                  // 1,228,800   (k1 -> k3)
    float* t0_part   = ws + 1228800;        // 5,120,000   (k1 -> k2a)
    float* time_pre  = ws + 6348800;        //   102,400   (k2a -> k3)
    float* view_part = ws + 6451200;        //     6,400   (k1 -> k3)
    float* tstat_part= ws + 6457600;        //       400   (k2a -> k3)
    float* sum2_raw  = ws + 6458408;        // 1,331,200   (k3 -> k5)
    float* chan_part = ws + 7789608;        //    49,152   (k3 -> k5)
    float* xbar_part = ws + 7838888;        //    83,200   (k5 -> k6)
    __hip_bfloat16* y = (__hip_bfloat16*)ws; // k7 output over region A
    // Region B (persistent past k7):
    float* scale_vc  = ws + 15360000;       //     1,600   (k6 -> k7)
    float* col_part  = ws + 15361600;       // 5,120,000   (k7 -> k8b)
    float2* colAB    = (float2*)(ws + 20481600); // 3,200 floats (k8b -> k9)

    float* out      = (float*)d_out;
    float* out_time = out + 30720000;

    k1_viewtime   <<<dim3(50,64), 256, 0, stream>>>(x0, Wv, Wt, view_pre, t0_part, view_part);
    k2a_timereduce<<<200, 256, 0, stream>>>(t0_part, time_pre, tstat_part);
    k3_conv       <<<dim3(6,64), 256, 0, stream>>>(time_pre, view_pre, view_part, tstat_part, Ws, g_t, be_t, g_v, be_v, sum2_raw, chan_part);
    k5_xbar       <<<dim3(82,4), 256, 0, stream>>>(sum2_raw, chan_part, g_s, be_s, xbar_part);
    k6_gates      <<<325, 64, 0, stream>>>(xbar_part, W2t, b2t, W2v, b2v, out_time, scale_vc);
    k7_mfma       <<<dim3(25,64), 256, 0, stream>>>(x0, scale_vc, Lw, y, col_part);
    k8b_colAB     <<<400, 256, 0, stream>>>(col_part, g_bn, be_bn, colAB);
    k9_final      <<<dim3(75,64), 256, 0, stream>>>(x0, y, colAB, out);
}